// Round 3
// baseline (45.256 us; speedup 1.0000x reference)
//
#include <hip/hip_runtime.h>

// center_loss: loss = (1/N) * sum_i ||feature[i] - center_vector[label[i]]||_2
// N=65536, D=512, C=10000, fp32 in/out.

#define N_SAMPLES 65536
#define DIM 512
#define GRID_BLOCKS 2048
#define BLOCK_THREADS 256
#define WAVES_PER_BLOCK 4
#define TOTAL_WAVES (GRID_BLOCKS * WAVES_PER_BLOCK)

__global__ __launch_bounds__(BLOCK_THREADS) void center_loss_pass1(
    const float* __restrict__ feature,
    const int* __restrict__ label,
    const float* __restrict__ center,
    float* __restrict__ partial) {
    __shared__ float wsum[WAVES_PER_BLOCK];

    const int wave = threadIdx.x >> 6;
    const int lane = threadIdx.x & 63;
    const int gwave0 = blockIdx.x * WAVES_PER_BLOCK + wave;

    float acc = 0.0f;

    for (int s = gwave0; s < N_SAMPLES; s += TOTAL_WAVES) {
        const int lab = label[s];
        // each lane owns 8 contiguous floats (2x float4) of the 512-dim row
        const float4* fp = reinterpret_cast<const float4*>(feature + (size_t)s * DIM) + lane * 2;
        const float4* cp = reinterpret_cast<const float4*>(center + (size_t)lab * DIM) + lane * 2;
        const float4 f0 = fp[0];
        const float4 f1 = fp[1];
        const float4 c0 = cp[0];
        const float4 c1 = cp[1];

        float ss = 0.0f, d;
        d = f0.x - c0.x; ss = fmaf(d, d, ss);
        d = f0.y - c0.y; ss = fmaf(d, d, ss);
        d = f0.z - c0.z; ss = fmaf(d, d, ss);
        d = f0.w - c0.w; ss = fmaf(d, d, ss);
        d = f1.x - c1.x; ss = fmaf(d, d, ss);
        d = f1.y - c1.y; ss = fmaf(d, d, ss);
        d = f1.z - c1.z; ss = fmaf(d, d, ss);
        d = f1.w - c1.w; ss = fmaf(d, d, ss);

        // 64-lane butterfly reduce
        #pragma unroll
        for (int off = 32; off > 0; off >>= 1)
            ss += __shfl_xor(ss, off, 64);

        if (lane == 0)
            acc += sqrtf(ss);
    }

    if (lane == 0) wsum[wave] = acc;
    __syncthreads();
    if (threadIdx.x == 0)
        partial[blockIdx.x] = wsum[0] + wsum[1] + wsum[2] + wsum[3];
}

__global__ __launch_bounds__(BLOCK_THREADS) void center_loss_pass2(
    const float* __restrict__ partial,
    float* __restrict__ out) {
    __shared__ float lds[WAVES_PER_BLOCK];
    const int wave = threadIdx.x >> 6;
    const int lane = threadIdx.x & 63;

    float s = 0.0f;
    for (int i = threadIdx.x; i < GRID_BLOCKS; i += BLOCK_THREADS)
        s += partial[i];

    #pragma unroll
    for (int off = 32; off > 0; off >>= 1)
        s += __shfl_xor(s, off, 64);

    if (lane == 0) lds[wave] = s;
    __syncthreads();
    if (threadIdx.x == 0)
        out[0] = (lds[0] + lds[1] + lds[2] + lds[3]) * (1.0f / (float)N_SAMPLES);
}

extern "C" void kernel_launch(void* const* d_in, const int* in_sizes, int n_in,
                              void* d_out, int out_size, void* d_ws, size_t ws_size,
                              hipStream_t stream) {
    const float* feature = (const float*)d_in[0];
    const int*   label   = (const int*)d_in[1];
    const float* center  = (const float*)d_in[2];
    float* out = (float*)d_out;
    float* partial = (float*)d_ws;  // GRID_BLOCKS floats = 8 KB

    center_loss_pass1<<<GRID_BLOCKS, BLOCK_THREADS, 0, stream>>>(feature, label, center, partial);
    center_loss_pass2<<<1, BLOCK_THREADS, 0, stream>>>(partial, out);
}